// Round 10
// baseline (90.565 us; speedup 1.0000x reference)
//
#include <hip/hip_runtime.h>

// Problem constants (from reference)
#define NQ 6
#define NF 4
#define GG 14
#define GG2 196
#define GG3 2744
#define NSIDE 12
#define PP 1728          // NSIDE^3
#define NC 40
#define BB 16
#define LAM 0.1f
#define FEAT_LEN (NF*PP*NQ)   // 41472
#define KCH 512
#define NCHUNK 81             // 41472 / 512
#define CTILES 5              // 40 / 8
#define NWAVE_IP2 (3456*4)    // ip2 entries (one per wave)

// ---------- sim: 8 lanes per circuit, 8 complex amps per lane ----------
// lane = f*16 + g*2 + c ; c = which batch-element of the wave's pair,
// g (3 bits) = state bits [5:3]: g0<->bit3(q2), g1<->bit4(q1), g2<->bit5(q0).
// local amp l (3 bits) = state bits [2:0]: bit2<->q3, bit1<->q4, bit0<->q5.
// block = 256 thr = 4 waves; block covers patch p = blockIdx>>1, batch half
// bh = blockIdx&1 (b = bh*8 + w*2 + c). Grid = 2*PP blocks.

__global__ __launch_bounds__(256) void sim_kernel(
    const float* __restrict__ x,      // [B,14,14,14]
    const float* __restrict__ theta,  // [NF,1,6,3]
    float* __restrict__ feats,        // [B][NF][PP][NQ]
    float* __restrict__ ip2)          // [NWAVE_IP2]
{
    const int t = threadIdx.x;
    const int w = t >> 6, lane = t & 63;
    const int c  = lane & 1;
    const int g0 = (lane >> 1) & 1, g1 = (lane >> 2) & 1, g2 = (lane >> 3) & 1;
    const int f  = (lane >> 4) & 3;
    const int p  = blockIdx.x >> 1;
    const int bh = blockIdx.x & 1;
    const int b  = bh*8 + w*2 + c;
    const int bl = w*2 + c;           // local batch index 0..7

    __shared__ __align__(16) float scrot[NF*NQ][8];   // 24 CRot 2x2 matrices
    __shared__ __align__(16) float scomp[8][NQ][4];   // composed enc columns

    const int px = p/(NSIDE*NSIDE), py = (p/NSIDE)%NSIDE, pz = p%NSIDE;

    // threads 64..87: CRot matrices (block-invariant)
    if (t >= 64 && t < 64 + NF*NQ) {
        const int j = t - 64;
        const float* a = theta + j*3;
        float s, cc, sap, cap, sam, cam;
        __sincosf(0.5f*a[1], &s, &cc);
        __sincosf(0.5f*(a[0]+a[2]), &sap, &cap);
        __sincosf(0.5f*(a[0]-a[2]), &sam, &cam);
        scrot[j][0] =  cap*cc; scrot[j][1] = -sap*cc;
        scrot[j][2] = -cam*s;  scrot[j][3] = -sam*s;
        scrot[j][4] =  cam*s;  scrot[j][5] = -sam*s;
        scrot[j][6] =  cap*cc; scrot[j][7] =  sap*cc;
    }
    // threads 0..47: composed encoding columns for (bl2, q)
    if (t < 8*NQ) {
        const int bl2 = t / NQ, q = t % NQ;
        const int b2 = bh*8 + bl2;
        const float* xp = x + (size_t)b2*GG3 + px*GG2 + py*GG + pz;
        #define SPV(i) xp[((i)/9)*GG2 + (((i)/3)%3)*GG + ((i)%3)]
        float s, cc, sap, cap, sam, cam;
        __sincosf(0.5f*SPV(3*q+1), &s, &cc);
        __sincosf(0.5f*(SPV(3*q)+SPV(3*q+2)), &sap, &cap);
        __sincosf(0.5f*(SPV(3*q)-SPV(3*q+2)), &sam, &cam);
        float c0r = cap*cc, c0i = -sap*cc, c1r = cam*s, c1i = -sam*s;
        if (q < 3) {   // compose with gate q+6 (applied second)
            const int k2 = 3*(q+6);
            float s_,c_,sap_,cap_,sam_,cam_;
            __sincosf(0.5f*SPV(k2+1), &s_, &c_);
            __sincosf(0.5f*(SPV(k2)+SPV(k2+2)), &sap_, &cap_);
            __sincosf(0.5f*(SPV(k2)-SPV(k2+2)), &sam_, &cam_);
            float b00r=cap_*c_, b00i=-sap_*c_, b01r=-cam_*s_, b01i=-sam_*s_;
            float b10r=cam_*s_, b10i=-sam_*s_, b11r=cap_*c_,  b11i= sap_*c_;
            float n0r = b00r*c0r - b00i*c0i + b01r*c1r - b01i*c1i;
            float n0i = b00r*c0i + b00i*c0r + b01r*c1i + b01i*c1r;
            float n1r = b10r*c0r - b10i*c0i + b11r*c1r - b11i*c1i;
            float n1i = b10r*c0i + b10i*c0r + b11r*c1i + b11i*c1r;
            c0r=n0r; c0i=n0i; c1r=n1r; c1i=n1i;
        }
        #undef SPV
        scomp[bl2][q][0]=c0r; scomp[bl2][q][1]=c0i;
        scomp[bl2][q][2]=c1r; scomp[bl2][q][3]=c1i;
    }
    __syncthreads();

    // ---- encoding: product state. Lane prefactor from qubits 0,1,2;
    // local 8-amp tensor ladder from qubits 3,4,5.
    float ar[8], ai[8];
    {
        float4 C0 = *(const float4*)&scomp[bl][0][0];
        float4 C1 = *(const float4*)&scomp[bl][1][0];
        float4 C2 = *(const float4*)&scomp[bl][2][0];
        float e0r = g2 ? C0.z : C0.x, e0i = g2 ? C0.w : C0.y;
        float e1r = g1 ? C1.z : C1.x, e1i = g1 ? C1.w : C1.y;
        float e2r = g0 ? C2.z : C2.x, e2i = g0 ? C2.w : C2.y;
        float t01r = e0r*e1r - e0i*e1i, t01i = e0r*e1i + e0i*e1r;
        float pfr = t01r*e2r - t01i*e2i, pfi = t01r*e2i + t01i*e2r;
        float4 C3 = *(const float4*)&scomp[bl][3][0];
        float4 C4 = *(const float4*)&scomp[bl][4][0];
        float4 C5 = *(const float4*)&scomp[bl][5][0];
        // q3 spread (mask4) from {0}
        ar[4] = C3.z*pfr - C3.w*pfi;  ai[4] = C3.z*pfi + C3.w*pfr;
        ar[0] = C3.x*pfr - C3.y*pfi;  ai[0] = C3.x*pfi + C3.y*pfr;
        // q4 spread (mask2) on {0,4}
        #pragma unroll
        for (int l = 0; l <= 4; l += 4) {
            float r0 = ar[l], i0 = ai[l];
            ar[l+2] = C4.z*r0 - C4.w*i0;  ai[l+2] = C4.z*i0 + C4.w*r0;
            ar[l]   = C4.x*r0 - C4.y*i0;  ai[l]   = C4.x*i0 + C4.y*r0;
        }
        // q5 spread (mask1) on {0,2,4,6}
        #pragma unroll
        for (int l = 0; l <= 6; l += 2) {
            float r0 = ar[l], i0 = ai[l];
            ar[l+1] = C5.z*r0 - C5.w*i0;  ai[l+1] = C5.z*i0 + C5.w*r0;
            ar[l]   = C5.x*r0 - C5.y*i0;  ai[l]   = C5.x*i0 + C5.y*r0;
        }
    }

    // ---- CRot ring for feature f (ctrl i -> tgt (i+1)%6)
    // CR0: ctrl q0(g2), tgt q1(g1) -> cross lane-xor 4
    {
        float4 A  = *(const float4*)&scrot[f*NQ+0][0];
        float4 Bq = *(const float4*)&scrot[f*NQ+0][4];
        float cAr = g1 ? Bq.z : A.x, cAi = g1 ? Bq.w : A.y;
        float cBr = g1 ? Bq.x : A.z, cBi = g1 ? Bq.y : A.w;
        if (!g2) { cAr = 1.f; cAi = 0.f; cBr = 0.f; cBi = 0.f; }
        #pragma unroll
        for (int l = 0; l < 8; ++l) {
            float prr = __shfl_xor(ar[l], 4), pri = __shfl_xor(ai[l], 4);
            float nr = cAr*ar[l] - cAi*ai[l] + cBr*prr - cBi*pri;
            float ni = cAr*ai[l] + cAi*ar[l] + cBr*pri + cBi*prr;
            ar[l] = nr; ai[l] = ni;
        }
    }
    // CR1: ctrl q1(g1), tgt q2(g0) -> cross lane-xor 2
    {
        float4 A  = *(const float4*)&scrot[f*NQ+1][0];
        float4 Bq = *(const float4*)&scrot[f*NQ+1][4];
        float cAr = g0 ? Bq.z : A.x, cAi = g0 ? Bq.w : A.y;
        float cBr = g0 ? Bq.x : A.z, cBi = g0 ? Bq.y : A.w;
        if (!g1) { cAr = 1.f; cAi = 0.f; cBr = 0.f; cBi = 0.f; }
        #pragma unroll
        for (int l = 0; l < 8; ++l) {
            float prr = __shfl_xor(ar[l], 2), pri = __shfl_xor(ai[l], 2);
            float nr = cAr*ar[l] - cAi*ai[l] + cBr*prr - cBi*pri;
            float ni = cAr*ai[l] + cAi*ar[l] + cBr*pri + cBi*prr;
            ar[l] = nr; ai[l] = ni;
        }
    }
    // CR2: ctrl q2(g0), tgt q3(local mask4): full 2x2 on 4 pairs, identity if !g0
    {
        float4 A  = *(const float4*)&scrot[f*NQ+2][0];
        float4 Bq = *(const float4*)&scrot[f*NQ+2][4];
        if (!g0) { A = make_float4(1.f,0.f,0.f,0.f); Bq = make_float4(0.f,0.f,1.f,0.f); }
        #pragma unroll
        for (int l = 0; l < 4; ++l) {
            const int l1 = l + 4;
            float a0r=ar[l], a0i=ai[l], a1r=ar[l1], a1i=ai[l1];
            ar[l]  = A.x*a0r - A.y*a0i + A.z*a1r - A.w*a1i;
            ai[l]  = A.x*a0i + A.y*a0r + A.z*a1i + A.w*a1r;
            ar[l1] = Bq.x*a0r - Bq.y*a0i + Bq.z*a1r - Bq.w*a1i;
            ai[l1] = Bq.x*a0i + Bq.y*a0r + Bq.z*a1i + Bq.w*a1r;
        }
    }
    // CR3: ctrl q3(bit2), tgt q4(bit1): sparse pairs (4,6),(5,7)
    {
        float4 A  = *(const float4*)&scrot[f*NQ+3][0];
        float4 Bq = *(const float4*)&scrot[f*NQ+3][4];
        #pragma unroll
        for (int l = 4; l < 6; ++l) {
            const int l1 = l + 2;
            float a0r=ar[l], a0i=ai[l], a1r=ar[l1], a1i=ai[l1];
            ar[l]  = A.x*a0r - A.y*a0i + A.z*a1r - A.w*a1i;
            ai[l]  = A.x*a0i + A.y*a0r + A.z*a1i + A.w*a1r;
            ar[l1] = Bq.x*a0r - Bq.y*a0i + Bq.z*a1r - Bq.w*a1i;
            ai[l1] = Bq.x*a0i + Bq.y*a0r + Bq.z*a1i + Bq.w*a1r;
        }
    }
    // CR4: ctrl q4(bit1), tgt q5(bit0): sparse pairs (2,3),(6,7)
    {
        float4 A  = *(const float4*)&scrot[f*NQ+4][0];
        float4 Bq = *(const float4*)&scrot[f*NQ+4][4];
        #pragma unroll
        for (int l = 2; l < 8; l += 4) {
            const int l1 = l + 1;
            float a0r=ar[l], a0i=ai[l], a1r=ar[l1], a1i=ai[l1];
            ar[l]  = A.x*a0r - A.y*a0i + A.z*a1r - A.w*a1i;
            ai[l]  = A.x*a0i + A.y*a0r + A.z*a1i + A.w*a1r;
            ar[l1] = Bq.x*a0r - Bq.y*a0i + Bq.z*a1r - Bq.w*a1i;
            ai[l1] = Bq.x*a0i + Bq.y*a0r + Bq.z*a1i + Bq.w*a1r;
        }
    }
    // CR5: ctrl q5(bit0 -> odd l only), tgt q0(g2) -> cross lane-xor 8
    {
        float4 A  = *(const float4*)&scrot[f*NQ+5][0];
        float4 Bq = *(const float4*)&scrot[f*NQ+5][4];
        float cAr = g2 ? Bq.z : A.x, cAi = g2 ? Bq.w : A.y;
        float cBr = g2 ? Bq.x : A.z, cBi = g2 ? Bq.y : A.w;
        #pragma unroll
        for (int l = 1; l < 8; l += 2) {
            float prr = __shfl_xor(ar[l], 8), pri = __shfl_xor(ai[l], 8);
            float nr = cAr*ar[l] - cAi*ai[l] + cBr*prr - cBi*pri;
            float ni = cAr*ai[l] + cAi*ar[l] + cBr*pri + cBi*prr;
            ar[l] = nr; ai[l] = ni;
        }
    }

    // ---- probabilities
    float pr[8];
    #pragma unroll
    for (int l = 0; l < 8; ++l) pr[l] = ar[l]*ar[l] + ai[l]*ai[l];

    // ---- loss pair-dots: f-partners at lane-xor 16,32,48; g-reduce xor 2,4,8
    float lc = 0.f;
    #pragma unroll
    for (int xi = 0; xi < 3; ++xi) {
        const int xm = (xi + 1) << 4;
        float d = 0.f;
        #pragma unroll
        for (int l = 0; l < 8; ++l) d += pr[l] * __shfl_xor(pr[l], xm);
        d += __shfl_xor(d, 2);
        d += __shfl_xor(d, 4);
        d += __shfl_xor(d, 8);
        lc += d*d;
    }
    #pragma unroll
    for (int m = 1; m < 64; m <<= 1) lc += __shfl_xor(lc, m);
    if (lane == 0) ip2[blockIdx.x*4 + w] = lc;   // 8x-counted; finalize /8

    // ---- expvals: local signed sums (q3,q4,q5), total s with g-signs (q0,q1,q2)
    float e3 = (pr[0]+pr[1]+pr[2]+pr[3]) - (pr[4]+pr[5]+pr[6]+pr[7]);
    float e4 = (pr[0]+pr[1]+pr[4]+pr[5]) - (pr[2]+pr[3]+pr[6]+pr[7]);
    float e5 = (pr[0]+pr[2]+pr[4]+pr[6]) - (pr[1]+pr[3]+pr[5]+pr[7]);
    float s  = (pr[0]+pr[1]+pr[2]+pr[3]) + (pr[4]+pr[5]+pr[6]+pr[7]);
    float e0 = g2 ? -s : s;
    float e1 = g1 ? -s : s;
    float e2 = g0 ? -s : s;
    #define GRED(e) { e += __shfl_xor(e, 2); e += __shfl_xor(e, 4); e += __shfl_xor(e, 8); }
    GRED(e0) GRED(e1) GRED(e2) GRED(e3) GRED(e4) GRED(e5)
    #undef GRED

    if (((lane >> 1) & 7) == 0) {     // one lane per (c,f)
        float* fo = feats + (((size_t)b*NF + f)*PP + p)*NQ;
        fo[0]=e0; fo[1]=e1; fo[2]=e2; fo[3]=e3; fo[4]=e4; fo[5]=e5;
    }
}

// ---------- logits phase A: K-split, W read once ----------

__global__ __launch_bounds__(128) void logitsA(
    const float* __restrict__ feats,   // [BB][FEAT_LEN]
    const float* __restrict__ W,       // [NC][FEAT_LEN]
    float* __restrict__ partial)       // [NC][BB][NCHUNK]
{
    const int chunk = blockIdx.x;      // 0..80
    const int ctile = blockIdx.y;      // 0..4
    const int t = threadIdx.x;         // 128
    const int jbase = chunk * KCH;

    __shared__ __align__(16) float fs[BB][KCH + 4];

    #pragma unroll
    for (int i = 0; i < 16; ++i) {
        const int gi = i*128 + t;
        const int br = gi >> 7;
        const int c4 = gi & 127;
        float4 v = *(const float4*)(feats + (size_t)br*FEAT_LEN + jbase + c4*4);
        *(float4*)&fs[br][c4*4] = v;
    }
    __syncthreads();

    const int cl = t >> 4, b = t & 15;
    const int c = ctile*8 + cl;
    const float* wr = W + (size_t)c*FEAT_LEN + jbase;
    float acc = 0.f;
    #pragma unroll 8
    for (int j4 = 0; j4 < KCH/4; ++j4) {
        float4 wv = *(const float4*)(wr + j4*4);
        float4 fv = *(const float4*)&fs[b][j4*4];
        acc += wv.x*fv.x + wv.y*fv.y + wv.z*fv.z + wv.w*fv.w;
    }
    partial[((size_t)c*BB + b)*NCHUNK + chunk] = acc;
}

// ---------- phase B: logits reduce + bias, and loss reduce ----------

__global__ __launch_bounds__(768) void finalize_kernel(
    const float* __restrict__ partial, const float* __restrict__ bias,
    const float* __restrict__ ip2, float* __restrict__ out)
{
    const int t = threadIdx.x;
    if (t < BB*NC) {
        const int b = t / NC, c = t % NC;
        const float* pp = partial + ((size_t)c*BB + b)*NCHUNK;
        float acc = bias[c];
        #pragma unroll 27
        for (int i = 0; i < NCHUNK; ++i) acc += pp[i];
        out[t] = acc;
    } else if (t >= 704) {
        const int lane = t - 704;
        float acc = 0.f;
        for (int i = lane; i < NWAVE_IP2; i += 64) acc += ip2[i];
        #pragma unroll
        for (int m = 1; m < 64; m <<= 1) acc += __shfl_xor(acc, m);
        if (lane == 0)   // /8: dots replicated across the 8 g-lanes per wave-sum
            out[BB*NC] = acc * (LAM / (float)(NF*(NF-1)) / (float)BB * 0.125f);
    }
}

extern "C" void kernel_launch(void* const* d_in, const int* in_sizes, int n_in,
                              void* d_out, int out_size, void* d_ws, size_t ws_size,
                              hipStream_t stream) {
    const float* x     = (const float*)d_in[0];  // [16,14,14,14]
    const float* theta = (const float*)d_in[1];  // [4,1,6,3]
    const float* W     = (const float*)d_in[2];  // [40,41472]
    const float* bias  = (const float*)d_in[3];  // [40]
    float* out = (float*)d_out;                  // [640 logits][1 loss]

    float* feats   = (float*)d_ws;                       // BB*FEAT_LEN
    float* ip2     = feats + (size_t)BB * FEAT_LEN;      // NWAVE_IP2
    float* partial = ip2 + NWAVE_IP2;                    // NC*BB*NCHUNK

    sim_kernel<<<2*PP, 256, 0, stream>>>(x, theta, feats, ip2);
    logitsA<<<dim3(NCHUNK, CTILES), 128, 0, stream>>>(feats, W, partial);
    finalize_kernel<<<1, 768, 0, stream>>>(partial, bias, ip2, out);
}

// Round 11
// 39.342 us; speedup vs baseline: 2.3020x; 2.3020x over previous
//
#include <hip/hip_runtime.h>

// Problem constants (from reference)
#define NQ 6
#define NF 4
#define GG 14
#define GG2 196
#define GG3 2744
#define NSIDE 12
#define PP 1728          // NSIDE^3
#define NC 40
#define BB 16
#define LAM 0.1f
#define FEAT_LEN (NF*PP*NQ)   // 41472
#define KCH 512
#define NCHUNK 81             // 41472 / 512
#define CTILES 5              // 40 / 8
#define NWAVE_IP2 (3456*4)    // ip2 entries (one per wave) = 13824 = 128*108

// ---------- sim: 8 lanes per circuit, 8 complex amps per lane ----------
// lane = f*16 + g*2 + c ; c = which batch-element of the wave's pair,
// g (3 bits) = state bits [5:3]: g0<->bit3(q2), g1<->bit4(q1), g2<->bit5(q0).
// local amp l (3 bits) = state bits [2:0]: bit2<->q3, bit1<->q4, bit0<->q5.
// block = 256 thr = 4 waves; block covers patch p = blockIdx>>1, batch half
// bh = blockIdx&1 (b = bh*8 + w*2 + c). Grid = 2*PP blocks.

__global__ __launch_bounds__(256) void sim_kernel(
    const float* __restrict__ x,      // [B,14,14,14]
    const float* __restrict__ theta,  // [NF,1,6,3]
    float* __restrict__ feats,        // [B][NF][PP][NQ]
    float* __restrict__ ip2)          // [NWAVE_IP2]
{
    const int t = threadIdx.x;
    const int w = t >> 6, lane = t & 63;
    const int c  = lane & 1;
    const int g0 = (lane >> 1) & 1, g1 = (lane >> 2) & 1, g2 = (lane >> 3) & 1;
    const int f  = (lane >> 4) & 3;
    const int p  = blockIdx.x >> 1;
    const int bh = blockIdx.x & 1;
    const int b  = bh*8 + w*2 + c;
    const int bl = w*2 + c;           // local batch index 0..7

    __shared__ __align__(16) float scrot[NF*NQ][8];   // 24 CRot 2x2 matrices
    __shared__ __align__(16) float scomp[8][NQ][4];   // composed enc columns

    const int px = p/(NSIDE*NSIDE), py = (p/NSIDE)%NSIDE, pz = p%NSIDE;

    // threads 64..87: CRot matrices (block-invariant)
    if (t >= 64 && t < 64 + NF*NQ) {
        const int j = t - 64;
        const float* a = theta + j*3;
        float s, cc, sap, cap, sam, cam;
        __sincosf(0.5f*a[1], &s, &cc);
        __sincosf(0.5f*(a[0]+a[2]), &sap, &cap);
        __sincosf(0.5f*(a[0]-a[2]), &sam, &cam);
        scrot[j][0] =  cap*cc; scrot[j][1] = -sap*cc;
        scrot[j][2] = -cam*s;  scrot[j][3] = -sam*s;
        scrot[j][4] =  cam*s;  scrot[j][5] = -sam*s;
        scrot[j][6] =  cap*cc; scrot[j][7] =  sap*cc;
    }
    // threads 0..47: composed encoding columns for (bl2, q)
    if (t < 8*NQ) {
        const int bl2 = t / NQ, q = t % NQ;
        const int b2 = bh*8 + bl2;
        const float* xp = x + (size_t)b2*GG3 + px*GG2 + py*GG + pz;
        #define SPV(i) xp[((i)/9)*GG2 + (((i)/3)%3)*GG + ((i)%3)]
        float s, cc, sap, cap, sam, cam;
        __sincosf(0.5f*SPV(3*q+1), &s, &cc);
        __sincosf(0.5f*(SPV(3*q)+SPV(3*q+2)), &sap, &cap);
        __sincosf(0.5f*(SPV(3*q)-SPV(3*q+2)), &sam, &cam);
        float c0r = cap*cc, c0i = -sap*cc, c1r = cam*s, c1i = -sam*s;
        if (q < 3) {   // compose with gate q+6 (applied second)
            const int k2 = 3*(q+6);
            float s_,c_,sap_,cap_,sam_,cam_;
            __sincosf(0.5f*SPV(k2+1), &s_, &c_);
            __sincosf(0.5f*(SPV(k2)+SPV(k2+2)), &sap_, &cap_);
            __sincosf(0.5f*(SPV(k2)-SPV(k2+2)), &sam_, &cam_);
            float b00r=cap_*c_, b00i=-sap_*c_, b01r=-cam_*s_, b01i=-sam_*s_;
            float b10r=cam_*s_, b10i=-sam_*s_, b11r=cap_*c_,  b11i= sap_*c_;
            float n0r = b00r*c0r - b00i*c0i + b01r*c1r - b01i*c1i;
            float n0i = b00r*c0i + b00i*c0r + b01r*c1i + b01i*c1r;
            float n1r = b10r*c0r - b10i*c0i + b11r*c1r - b11i*c1i;
            float n1i = b10r*c0i + b10i*c0r + b11r*c1i + b11i*c1r;
            c0r=n0r; c0i=n0i; c1r=n1r; c1i=n1i;
        }
        #undef SPV
        scomp[bl2][q][0]=c0r; scomp[bl2][q][1]=c0i;
        scomp[bl2][q][2]=c1r; scomp[bl2][q][3]=c1i;
    }
    __syncthreads();

    // ---- encoding: product state. Lane prefactor from qubits 0,1,2;
    // local 8-amp tensor ladder from qubits 3,4,5.
    float ar[8], ai[8];
    {
        float4 C0 = *(const float4*)&scomp[bl][0][0];
        float4 C1 = *(const float4*)&scomp[bl][1][0];
        float4 C2 = *(const float4*)&scomp[bl][2][0];
        float e0r = g2 ? C0.z : C0.x, e0i = g2 ? C0.w : C0.y;
        float e1r = g1 ? C1.z : C1.x, e1i = g1 ? C1.w : C1.y;
        float e2r = g0 ? C2.z : C2.x, e2i = g0 ? C2.w : C2.y;
        float t01r = e0r*e1r - e0i*e1i, t01i = e0r*e1i + e0i*e1r;
        float pfr = t01r*e2r - t01i*e2i, pfi = t01r*e2i + t01i*e2r;
        float4 C3 = *(const float4*)&scomp[bl][3][0];
        float4 C4 = *(const float4*)&scomp[bl][4][0];
        float4 C5 = *(const float4*)&scomp[bl][5][0];
        // q3 spread (mask4) from {0}
        ar[4] = C3.z*pfr - C3.w*pfi;  ai[4] = C3.z*pfi + C3.w*pfr;
        ar[0] = C3.x*pfr - C3.y*pfi;  ai[0] = C3.x*pfi + C3.y*pfr;
        // q4 spread (mask2) on {0,4}
        #pragma unroll
        for (int l = 0; l <= 4; l += 4) {
            float r0 = ar[l], i0 = ai[l];
            ar[l+2] = C4.z*r0 - C4.w*i0;  ai[l+2] = C4.z*i0 + C4.w*r0;
            ar[l]   = C4.x*r0 - C4.y*i0;  ai[l]   = C4.x*i0 + C4.y*r0;
        }
        // q5 spread (mask1) on {0,2,4,6}
        #pragma unroll
        for (int l = 0; l <= 6; l += 2) {
            float r0 = ar[l], i0 = ai[l];
            ar[l+1] = C5.z*r0 - C5.w*i0;  ai[l+1] = C5.z*i0 + C5.w*r0;
            ar[l]   = C5.x*r0 - C5.y*i0;  ai[l]   = C5.x*i0 + C5.y*r0;
        }
    }

    // ---- CRot ring for feature f (ctrl i -> tgt (i+1)%6)
    // CR0: ctrl q0(g2), tgt q1(g1) -> cross lane-xor 4
    {
        float4 A  = *(const float4*)&scrot[f*NQ+0][0];
        float4 Bq = *(const float4*)&scrot[f*NQ+0][4];
        float cAr = g1 ? Bq.z : A.x, cAi = g1 ? Bq.w : A.y;
        float cBr = g1 ? Bq.x : A.z, cBi = g1 ? Bq.y : A.w;
        if (!g2) { cAr = 1.f; cAi = 0.f; cBr = 0.f; cBi = 0.f; }
        #pragma unroll
        for (int l = 0; l < 8; ++l) {
            float prr = __shfl_xor(ar[l], 4), pri = __shfl_xor(ai[l], 4);
            float nr = cAr*ar[l] - cAi*ai[l] + cBr*prr - cBi*pri;
            float ni = cAr*ai[l] + cAi*ar[l] + cBr*pri + cBi*prr;
            ar[l] = nr; ai[l] = ni;
        }
    }
    // CR1: ctrl q1(g1), tgt q2(g0) -> cross lane-xor 2
    {
        float4 A  = *(const float4*)&scrot[f*NQ+1][0];
        float4 Bq = *(const float4*)&scrot[f*NQ+1][4];
        float cAr = g0 ? Bq.z : A.x, cAi = g0 ? Bq.w : A.y;
        float cBr = g0 ? Bq.x : A.z, cBi = g0 ? Bq.y : A.w;
        if (!g1) { cAr = 1.f; cAi = 0.f; cBr = 0.f; cBi = 0.f; }
        #pragma unroll
        for (int l = 0; l < 8; ++l) {
            float prr = __shfl_xor(ar[l], 2), pri = __shfl_xor(ai[l], 2);
            float nr = cAr*ar[l] - cAi*ai[l] + cBr*prr - cBi*pri;
            float ni = cAr*ai[l] + cAi*ar[l] + cBr*pri + cBi*prr;
            ar[l] = nr; ai[l] = ni;
        }
    }
    // CR2: ctrl q2(g0), tgt q3(local mask4): full 2x2 on 4 pairs, identity if !g0
    {
        float4 A  = *(const float4*)&scrot[f*NQ+2][0];
        float4 Bq = *(const float4*)&scrot[f*NQ+2][4];
        if (!g0) { A = make_float4(1.f,0.f,0.f,0.f); Bq = make_float4(0.f,0.f,1.f,0.f); }
        #pragma unroll
        for (int l = 0; l < 4; ++l) {
            const int l1 = l + 4;
            float a0r=ar[l], a0i=ai[l], a1r=ar[l1], a1i=ai[l1];
            ar[l]  = A.x*a0r - A.y*a0i + A.z*a1r - A.w*a1i;
            ai[l]  = A.x*a0i + A.y*a0r + A.z*a1i + A.w*a1r;
            ar[l1] = Bq.x*a0r - Bq.y*a0i + Bq.z*a1r - Bq.w*a1i;
            ai[l1] = Bq.x*a0i + Bq.y*a0r + Bq.z*a1i + Bq.w*a1r;
        }
    }
    // CR3: ctrl q3(bit2), tgt q4(bit1): sparse pairs (4,6),(5,7)
    {
        float4 A  = *(const float4*)&scrot[f*NQ+3][0];
        float4 Bq = *(const float4*)&scrot[f*NQ+3][4];
        #pragma unroll
        for (int l = 4; l < 6; ++l) {
            const int l1 = l + 2;
            float a0r=ar[l], a0i=ai[l], a1r=ar[l1], a1i=ai[l1];
            ar[l]  = A.x*a0r - A.y*a0i + A.z*a1r - A.w*a1i;
            ai[l]  = A.x*a0i + A.y*a0r + A.z*a1i + A.w*a1r;
            ar[l1] = Bq.x*a0r - Bq.y*a0i + Bq.z*a1r - Bq.w*a1i;
            ai[l1] = Bq.x*a0i + Bq.y*a0r + Bq.z*a1i + Bq.w*a1r;
        }
    }
    // CR4: ctrl q4(bit1), tgt q5(bit0): sparse pairs (2,3),(6,7)
    {
        float4 A  = *(const float4*)&scrot[f*NQ+4][0];
        float4 Bq = *(const float4*)&scrot[f*NQ+4][4];
        #pragma unroll
        for (int l = 2; l < 8; l += 4) {
            const int l1 = l + 1;
            float a0r=ar[l], a0i=ai[l], a1r=ar[l1], a1i=ai[l1];
            ar[l]  = A.x*a0r - A.y*a0i + A.z*a1r - A.w*a1i;
            ai[l]  = A.x*a0i + A.y*a0r + A.z*a1i + A.w*a1r;
            ar[l1] = Bq.x*a0r - Bq.y*a0i + Bq.z*a1r - Bq.w*a1i;
            ai[l1] = Bq.x*a0i + Bq.y*a0r + Bq.z*a1i + Bq.w*a1r;
        }
    }
    // CR5: ctrl q5(bit0 -> odd l only), tgt q0(g2) -> cross lane-xor 8
    {
        float4 A  = *(const float4*)&scrot[f*NQ+5][0];
        float4 Bq = *(const float4*)&scrot[f*NQ+5][4];
        float cAr = g2 ? Bq.z : A.x, cAi = g2 ? Bq.w : A.y;
        float cBr = g2 ? Bq.x : A.z, cBi = g2 ? Bq.y : A.w;
        #pragma unroll
        for (int l = 1; l < 8; l += 2) {
            float prr = __shfl_xor(ar[l], 8), pri = __shfl_xor(ai[l], 8);
            float nr = cAr*ar[l] - cAi*ai[l] + cBr*prr - cBi*pri;
            float ni = cAr*ai[l] + cAi*ar[l] + cBr*pri + cBi*prr;
            ar[l] = nr; ai[l] = ni;
        }
    }

    // ---- probabilities
    float pr[8];
    #pragma unroll
    for (int l = 0; l < 8; ++l) pr[l] = ar[l]*ar[l] + ai[l]*ai[l];

    // ---- loss pair-dots: f-partners at lane-xor 16,32,48; g-reduce xor 2,4,8
    float lc = 0.f;
    #pragma unroll
    for (int xi = 0; xi < 3; ++xi) {
        const int xm = (xi + 1) << 4;
        float d = 0.f;
        #pragma unroll
        for (int l = 0; l < 8; ++l) d += pr[l] * __shfl_xor(pr[l], xm);
        d += __shfl_xor(d, 2);
        d += __shfl_xor(d, 4);
        d += __shfl_xor(d, 8);
        lc += d*d;
    }
    #pragma unroll
    for (int m = 1; m < 64; m <<= 1) lc += __shfl_xor(lc, m);
    if (lane == 0) ip2[blockIdx.x*4 + w] = lc;   // 8x-counted; finalize /8

    // ---- expvals: local signed sums (q3,q4,q5), total s with g-signs (q0,q1,q2)
    float e3 = (pr[0]+pr[1]+pr[2]+pr[3]) - (pr[4]+pr[5]+pr[6]+pr[7]);
    float e4 = (pr[0]+pr[1]+pr[4]+pr[5]) - (pr[2]+pr[3]+pr[6]+pr[7]);
    float e5 = (pr[0]+pr[2]+pr[4]+pr[6]) - (pr[1]+pr[3]+pr[5]+pr[7]);
    float s  = (pr[0]+pr[1]+pr[2]+pr[3]) + (pr[4]+pr[5]+pr[6]+pr[7]);
    float e0 = g2 ? -s : s;
    float e1 = g1 ? -s : s;
    float e2 = g0 ? -s : s;
    #define GRED(e) { e += __shfl_xor(e, 2); e += __shfl_xor(e, 4); e += __shfl_xor(e, 8); }
    GRED(e0) GRED(e1) GRED(e2) GRED(e3) GRED(e4) GRED(e5)
    #undef GRED

    if (((lane >> 1) & 7) == 0) {     // one lane per (c,f)
        float* fo = feats + (((size_t)b*NF + f)*PP + p)*NQ;
        fo[0]=e0; fo[1]=e1; fo[2]=e2; fo[3]=e3; fo[4]=e4; fo[5]=e5;
    }
}

// ---------- logits phase A: K-split, W read once ----------
// partial layout: [NCHUNK][BB][NC] so finalize reads coalesced.

__global__ __launch_bounds__(128) void logitsA(
    const float* __restrict__ feats,   // [BB][FEAT_LEN]
    const float* __restrict__ W,       // [NC][FEAT_LEN]
    float* __restrict__ partial)       // [NCHUNK][BB][NC]
{
    const int chunk = blockIdx.x;      // 0..80
    const int ctile = blockIdx.y;      // 0..4
    const int t = threadIdx.x;         // 128
    const int jbase = chunk * KCH;

    __shared__ __align__(16) float fs[BB][KCH + 4];

    #pragma unroll
    for (int i = 0; i < 16; ++i) {
        const int gi = i*128 + t;
        const int br = gi >> 7;
        const int c4 = gi & 127;
        float4 v = *(const float4*)(feats + (size_t)br*FEAT_LEN + jbase + c4*4);
        *(float4*)&fs[br][c4*4] = v;
    }
    __syncthreads();

    const int cl = t >> 4, b = t & 15;
    const int c = ctile*8 + cl;
    const float* wr = W + (size_t)c*FEAT_LEN + jbase;
    float acc = 0.f;
    #pragma unroll 8
    for (int j4 = 0; j4 < KCH/4; ++j4) {
        float4 wv = *(const float4*)(wr + j4*4);
        float4 fv = *(const float4*)&fs[b][j4*4];
        acc += wv.x*fv.x + wv.y*fv.y + wv.z*fv.z + wv.w*fv.w;
    }
    partial[((size_t)chunk*BB + b)*NC + c] = acc;
}

// ---------- phase B: logits reduce + bias (coalesced), loss reduce (unrolled) ----------

__global__ __launch_bounds__(768) void finalize_kernel(
    const float* __restrict__ partial, const float* __restrict__ bias,
    const float* __restrict__ ip2, float* __restrict__ out)
{
    const int t = threadIdx.x;
    __shared__ float red[2];

    if (t >= 640) {
        // 128 threads: loss reduce over NWAVE_IP2 = 128 * 108 entries
        const int idx = t - 640;
        float acc = 0.f;
        #pragma unroll
        for (int k = 0; k < 108; ++k) acc += ip2[idx + k*128];
        #pragma unroll
        for (int m = 1; m < 64; m <<= 1) acc += __shfl_xor(acc, m);
        if ((idx & 63) == 0) red[idx >> 6] = acc;
    }
    __syncthreads();

    if (t < BB*NC) {
        const int b = t / NC, c = t % NC;   // consecutive t -> consecutive c
        float acc = bias[c];
        #pragma unroll
        for (int i = 0; i < NCHUNK; ++i)
            acc += partial[((size_t)i*BB + b)*NC + c];
        out[t] = acc;
    } else if (t == 640) {
        out[BB*NC] = (red[0] + red[1]) *
                     (LAM / (float)(NF*(NF-1)) / (float)BB * 0.125f);
    }
}

extern "C" void kernel_launch(void* const* d_in, const int* in_sizes, int n_in,
                              void* d_out, int out_size, void* d_ws, size_t ws_size,
                              hipStream_t stream) {
    const float* x     = (const float*)d_in[0];  // [16,14,14,14]
    const float* theta = (const float*)d_in[1];  // [4,1,6,3]
    const float* W     = (const float*)d_in[2];  // [40,41472]
    const float* bias  = (const float*)d_in[3];  // [40]
    float* out = (float*)d_out;                  // [640 logits][1 loss]

    float* feats   = (float*)d_ws;                       // BB*FEAT_LEN
    float* ip2     = feats + (size_t)BB * FEAT_LEN;      // NWAVE_IP2
    float* partial = ip2 + NWAVE_IP2;                    // NCHUNK*BB*NC

    sim_kernel<<<2*PP, 256, 0, stream>>>(x, theta, feats, ip2);
    logitsA<<<dim3(NCHUNK, CTILES), 128, 0, stream>>>(feats, W, partial);
    finalize_kernel<<<1, 768, 0, stream>>>(partial, bias, ip2, out);
}